// Round 1
// baseline (2360.055 us; speedup 1.0000x reference)
//
#include <hip/hip_runtime.h>
#include <hip/hip_bf16.h>

#define NC 200000
#define BB 1024
#define DD 128
#define DBH 256
#define CS 96

typedef __attribute__((ext_vector_type(8))) short bf16x8;
typedef __attribute__((ext_vector_type(4))) float f32x4;

// ============================ encoder stage 1: H = X @ W_in + b ============================
__global__ __launch_bounds__(256) void k_e1(const float* __restrict__ X,
                                            const float* __restrict__ W,
                                            const float* __restrict__ bias,
                                            float* __restrict__ H) {
  __shared__ float Xs[32 * 32];
  const int tid = threadIdx.x;
  const int r0 = blockIdx.x * 32;
  ((float4*)Xs)[tid] = ((const float4*)(X + (size_t)r0 * 32))[tid];
  __syncthreads();
  const int d0 = tid & 63;
  const int rh = tid >> 6;  // 4 groups of 8 rows
  float acc0[8], acc1[8];
  const float b0 = bias[d0], b1 = bias[d0 + 64];
#pragma unroll
  for (int r = 0; r < 8; ++r) { acc0[r] = b0; acc1[r] = b1; }
#pragma unroll
  for (int k4 = 0; k4 < 8; ++k4) {
    float w0[4], w1[4];
#pragma unroll
    for (int kk = 0; kk < 4; ++kk) {
      w0[kk] = W[(k4 * 4 + kk) * DD + d0];
      w1[kk] = W[(k4 * 4 + kk) * DD + d0 + 64];
    }
#pragma unroll
    for (int r = 0; r < 8; ++r) {
      float4 x4 = ((const float4*)(Xs + (rh * 8 + r) * 32))[k4];
      acc0[r] += x4.x * w0[0] + x4.y * w0[1] + x4.z * w0[2] + x4.w * w0[3];
      acc1[r] += x4.x * w1[0] + x4.y * w1[1] + x4.z * w1[2] + x4.w * w1[3];
    }
  }
#pragma unroll
  for (int r = 0; r < 8; ++r) {
    const size_t row = (size_t)(r0 + rh * 8 + r);
    H[row * DD + d0] = acc0[r];
    H[row * DD + d0 + 64] = acc1[r];
  }
}

// ================= encoder stage 2+3: H = H + relu(H@W1 + b1)@W2 + b2 =================
__global__ __launch_bounds__(256) void k_e23(float* __restrict__ H,
                                             const float* __restrict__ W1,
                                             const float* __restrict__ B1,
                                             const float* __restrict__ W2,
                                             const float* __restrict__ B2) {
  __shared__ float Hs[32 * DD];
  __shared__ float Ts[32 * DBH];
  const int tid = threadIdx.x;
  const int r0 = blockIdx.x * 32;
#pragma unroll
  for (int i = 0; i < 4; ++i)
    ((float4*)Hs)[tid + 256 * i] = ((const float4*)(H + (size_t)r0 * DD))[tid + 256 * i];
  __syncthreads();
  {  // phase 1: Ts = relu(Hs @ W1 + B1)   (thread: 2 cols x 16 rows)
    const int u0 = tid & 127, rh = tid >> 7;
    float a0[16], a1[16];
    const float b0 = B1[u0], b1 = B1[u0 + 128];
#pragma unroll
    for (int r = 0; r < 16; ++r) { a0[r] = b0; a1[r] = b1; }
    for (int j4 = 0; j4 < 32; ++j4) {
      float w0[4], w1[4];
#pragma unroll
      for (int jj = 0; jj < 4; ++jj) {
        w0[jj] = W1[(j4 * 4 + jj) * DBH + u0];
        w1[jj] = W1[(j4 * 4 + jj) * DBH + u0 + 128];
      }
#pragma unroll
      for (int r = 0; r < 16; ++r) {
        float4 h4 = ((const float4*)(Hs + (rh * 16 + r) * DD))[j4];
        a0[r] += h4.x * w0[0] + h4.y * w0[1] + h4.z * w0[2] + h4.w * w0[3];
        a1[r] += h4.x * w1[0] + h4.y * w1[1] + h4.z * w1[2] + h4.w * w1[3];
      }
    }
#pragma unroll
    for (int r = 0; r < 16; ++r) {
      Ts[(rh * 16 + r) * DBH + u0] = fmaxf(a0[r], 0.f);
      Ts[(rh * 16 + r) * DBH + u0 + 128] = fmaxf(a1[r], 0.f);
    }
  }
  __syncthreads();
  {  // phase 2: H = Hs + Ts @ W2 + B2   (thread: 2 cols x 8 rows)
    const int d0 = tid & 63, rh = tid >> 6;
    float a0[8], a1[8];
    const float b0 = B2[d0], b1 = B2[d0 + 64];
#pragma unroll
    for (int r = 0; r < 8; ++r) { a0[r] = b0; a1[r] = b1; }
    for (int u4 = 0; u4 < 64; ++u4) {
      float w0[4], w1[4];
#pragma unroll
      for (int uu = 0; uu < 4; ++uu) {
        w0[uu] = W2[(u4 * 4 + uu) * DD + d0];
        w1[uu] = W2[(u4 * 4 + uu) * DD + d0 + 64];
      }
#pragma unroll
      for (int r = 0; r < 8; ++r) {
        float4 t4 = ((const float4*)(Ts + (rh * 8 + r) * DBH))[u4];
        a0[r] += t4.x * w0[0] + t4.y * w0[1] + t4.z * w0[2] + t4.w * w0[3];
        a1[r] += t4.x * w1[0] + t4.y * w1[1] + t4.z * w1[2] + t4.w * w1[3];
      }
    }
#pragma unroll
    for (int r = 0; r < 8; ++r) {
      const size_t row = (size_t)(r0 + rh * 8 + r);
      H[row * DD + d0]      = Hs[(rh * 8 + r) * DD + d0] + a0[r];
      H[row * DD + d0 + 64] = Hs[(rh * 8 + r) * DD + d0 + 64] + a1[r];
    }
  }
}

// ============ encoder stage 4: K = LN(H)@Kw + Kb ; also bf16 copy + rowwise sum(K^2) ============
__global__ __launch_bounds__(256) void k_e4(const float* __restrict__ H,
                                            const float* __restrict__ g,
                                            const float* __restrict__ bln,
                                            const float* __restrict__ Kw,
                                            const float* __restrict__ Kb,
                                            float* __restrict__ Kout,
                                            __hip_bfloat16* __restrict__ Kb16,
                                            float* __restrict__ k2out) {
  __shared__ float Hs[32 * DD];
  __shared__ float Ls[32 * DD];
  __shared__ float red[32 * 8];
  __shared__ float mrow[32], srow[32];
  const int tid = threadIdx.x;
  const int r0 = blockIdx.x * 32;
#pragma unroll
  for (int i = 0; i < 4; ++i)
    ((float4*)Hs)[tid + 256 * i] = ((const float4*)(H + (size_t)r0 * DD))[tid + 256 * i];
  __syncthreads();
  const int row = tid >> 3, s8 = tid & 7;  // 32 rows x 8 threads
  {
    float ps = 0.f;
#pragma unroll
    for (int j = 0; j < 16; ++j) ps += Hs[row * DD + s8 * 16 + j];
    red[row * 8 + s8] = ps;
  }
  __syncthreads();
  if (s8 == 0) {
    float m = 0.f;
#pragma unroll
    for (int i = 0; i < 8; ++i) m += red[row * 8 + i];
    mrow[row] = m * (1.f / 128.f);
  }
  __syncthreads();
  const float m = mrow[row];
  {
    float ps = 0.f;
#pragma unroll
    for (int j = 0; j < 16; ++j) {
      float d = Hs[row * DD + s8 * 16 + j] - m;
      ps += d * d;
    }
    red[row * 8 + s8] = ps;
  }
  __syncthreads();
  if (s8 == 0) {
    float v = 0.f;
#pragma unroll
    for (int i = 0; i < 8; ++i) v += red[row * 8 + i];
    srow[row] = 1.f / sqrtf(v * (1.f / 128.f) + 1e-5f);
  }
  __syncthreads();
  const float rstd = srow[row];
#pragma unroll
  for (int j = 0; j < 16; ++j) {
    const int jj = s8 * 16 + j;
    Ls[row * DD + jj] = (Hs[row * DD + jj] - m) * rstd * g[jj] + bln[jj];
  }
  __syncthreads();
  // k = Ls @ Kw + Kb   (thread: 2 cols x 8 rows)
  const int d0 = tid & 63, rh = tid >> 6;
  float a0[8], a1[8];
  const float kb0 = Kb[d0], kb1 = Kb[d0 + 64];
#pragma unroll
  for (int r = 0; r < 8; ++r) { a0[r] = kb0; a1[r] = kb1; }
  for (int i4 = 0; i4 < 32; ++i4) {
    float w0[4], w1[4];
#pragma unroll
    for (int ii = 0; ii < 4; ++ii) {
      w0[ii] = Kw[(i4 * 4 + ii) * DD + d0];
      w1[ii] = Kw[(i4 * 4 + ii) * DD + d0 + 64];
    }
#pragma unroll
    for (int r = 0; r < 8; ++r) {
      float4 l4 = ((const float4*)(Ls + (rh * 8 + r) * DD))[i4];
      a0[r] += l4.x * w0[0] + l4.y * w0[1] + l4.z * w0[2] + l4.w * w0[3];
      a1[r] += l4.x * w1[0] + l4.y * w1[1] + l4.z * w1[2] + l4.w * w1[3];
    }
  }
#pragma unroll
  for (int r = 0; r < 8; ++r) {
    const int lr = rh * 8 + r;
    const size_t grow = (size_t)(r0 + lr);
    Kout[grow * DD + d0] = a0[r];
    Kout[grow * DD + d0 + 64] = a1[r];
    Kb16[grow * DD + d0] = __float2bfloat16(a0[r]);
    Kb16[grow * DD + d0 + 64] = __float2bfloat16(a1[r]);
    Hs[lr * DD + d0] = a0[r] * a0[r];          // reuse Hs for k^2 partials
    Hs[lr * DD + d0 + 64] = a1[r] * a1[r];
  }
  __syncthreads();
  {
    float ps = 0.f;
#pragma unroll
    for (int j = 0; j < 16; ++j) ps += Hs[row * DD + s8 * 16 + j];
    red[row * 8 + s8] = ps;
  }
  __syncthreads();
  if (s8 == 0) {
    float v = 0.f;
#pragma unroll
    for (int i = 0; i < 8; ++i) v += red[row * 8 + i];
    k2out[r0 + row] = v;
  }
}

// ================= sims GEMM: S[m][n] = bf16( dot(A[m],B[n]) - 0.5*ck2[n] ) =================
// A: [256,128] bf16 (chunk of x-side k), B: [NC,128] bf16 (cand_k), S: [256,NC] bf16
#define LDT 136  // padded LDS row stride in bf16 elems
__global__ __launch_bounds__(256) void k_sims(const __hip_bfloat16* __restrict__ A,
                                              const __hip_bfloat16* __restrict__ Bm,
                                              const float* __restrict__ ck2,
                                              __hip_bfloat16* __restrict__ S) {
  __shared__ __hip_bfloat16 As[64 * LDT];
  __shared__ __hip_bfloat16 Bs[64 * LDT];
  const int tid = threadIdx.x;
  const int n0 = blockIdx.x * 64;
  const int m0 = blockIdx.y * 64;
  {
    const uint4* ga = (const uint4*)(A + (size_t)m0 * DD);
    const uint4* gb = (const uint4*)(Bm + (size_t)n0 * DD);
#pragma unroll
    for (int i = 0; i < 4; ++i) {
      const int e8 = i * 256 + tid;   // 8-elem group id, 0..1023
      const int row = e8 >> 4;
      const int c8 = e8 & 15;
      uint4 va = ga[e8];
      uint4 vb = gb[e8];
      *(uint4*)(As + row * LDT + c8 * 8) = va;
      *(uint4*)(Bs + row * LDT + c8 * 8) = vb;
    }
  }
  __syncthreads();
  const int l = tid & 63, w = tid >> 6;
  const int wm = w >> 1, wn = w & 1;
  const int lr = l & 15, lg = l >> 4;
  f32x4 acc[2][2] = {};
#pragma unroll
  for (int kk = 0; kk < 4; ++kk) {
    bf16x8 a[2], b[2];
#pragma unroll
    for (int mi = 0; mi < 2; ++mi)
      a[mi] = *(const bf16x8*)(As + (wm * 32 + mi * 16 + lr) * LDT + kk * 32 + lg * 8);
#pragma unroll
    for (int ni = 0; ni < 2; ++ni)
      b[ni] = *(const bf16x8*)(Bs + (wn * 32 + ni * 16 + lr) * LDT + kk * 32 + lg * 8);
#pragma unroll
    for (int mi = 0; mi < 2; ++mi)
#pragma unroll
      for (int ni = 0; ni < 2; ++ni)
        acc[mi][ni] = __builtin_amdgcn_mfma_f32_16x16x32_bf16(a[mi], b[ni], acc[mi][ni], 0, 0, 0);
  }
#pragma unroll
  for (int mi = 0; mi < 2; ++mi)
#pragma unroll
    for (int ni = 0; ni < 2; ++ni) {
      const int gcol = n0 + wn * 32 + ni * 16 + lr;
      const float c2 = 0.5f * ck2[gcol];
#pragma unroll
      for (int r = 0; r < 4; ++r) {
        const int grow = m0 + wm * 32 + mi * 16 + lg * 4 + r;
        S[(size_t)grow * NC + gcol] = __float2bfloat16(acc[mi][ni][r] - c2);
      }
    }
}

// ======================= per-row top-96 selection from bf16 score row =======================
__device__ inline unsigned long long mkkey(float v, int idx) {
  unsigned b = __float_as_uint(v);
  unsigned u = (b & 0x80000000u) ? ~b : (b | 0x80000000u);
  return (((unsigned long long)(~u)) << 32) | (unsigned)idx;
}

#define SCAP 4096
__global__ __launch_bounds__(256) void k_select(const __hip_bfloat16* __restrict__ S,
                                                int* __restrict__ idx_out) {
  __shared__ unsigned long long keys[SCAP];
  __shared__ float redmax[256];
  __shared__ int cnt_sh;
  const int tid = threadIdx.x;
  const unsigned* row = (const unsigned*)(S + (size_t)blockIdx.x * NC);  // 2 bf16 per word
  const int NW = NC / 8;  // uint4 groups: 25000
  // pass 1: row max
  float m = -1e30f;
  for (int v = tid; v < NW; v += 256) {
    uint4 d = ((const uint4*)row)[v];
    unsigned wd0 = d.x, wd1 = d.y, wd2 = d.z, wd3 = d.w;
    m = fmaxf(m, __uint_as_float(wd0 << 16)); m = fmaxf(m, __uint_as_float(wd0 & 0xffff0000u));
    m = fmaxf(m, __uint_as_float(wd1 << 16)); m = fmaxf(m, __uint_as_float(wd1 & 0xffff0000u));
    m = fmaxf(m, __uint_as_float(wd2 << 16)); m = fmaxf(m, __uint_as_float(wd2 & 0xffff0000u));
    m = fmaxf(m, __uint_as_float(wd3 << 16)); m = fmaxf(m, __uint_as_float(wd3 & 0xffff0000u));
  }
  redmax[tid] = m;
  __syncthreads();
  for (int s = 128; s > 0; s >>= 1) {
    if (tid < s) redmax[tid] = fmaxf(redmax[tid], redmax[tid + s]);
    __syncthreads();
  }
  m = redmax[0];
  // adaptive collect
  float W = 7.0f;
  int cnt = 0;
  for (int it = 0; it < 24; ++it) {
    __syncthreads();
    if (tid == 0) cnt_sh = 0;
    __syncthreads();
    const float thr = m - W;
    for (int v = tid; v < NW; v += 256) {
      uint4 d = ((const uint4*)row)[v];
      const unsigned wd[4] = {d.x, d.y, d.z, d.w};
#pragma unroll
      for (int wi = 0; wi < 4; ++wi) {
        float vlo = __uint_as_float(wd[wi] << 16);
        float vhi = __uint_as_float(wd[wi] & 0xffff0000u);
        int base = v * 8 + wi * 2;
        if (vlo >= thr) { int p = atomicAdd(&cnt_sh, 1); if (p < SCAP) keys[p] = mkkey(vlo, base); }
        if (vhi >= thr) { int p = atomicAdd(&cnt_sh, 1); if (p < SCAP) keys[p] = mkkey(vhi, base + 1); }
      }
    }
    __syncthreads();
    cnt = cnt_sh;
    if (cnt >= CS && cnt <= SCAP) break;
    W = (cnt < CS) ? W * 2.0f : W * 0.6f;
  }
  if (cnt > SCAP) cnt = SCAP;
  int size = 128;
  while (size < cnt) size <<= 1;
  for (int i = tid; i < size; i += 256)
    if (i >= cnt) keys[i] = 0xFFFFFFFFFFFFFFFFull;
  __syncthreads();
  // bitonic sort ascending (key = ~sortable(val) : idx  =>  val desc, idx asc)
  for (int k = 2; k <= size; k <<= 1) {
    for (int j = k >> 1; j > 0; j >>= 1) {
      for (int i = tid; i < size; i += 256) {
        const int ixj = i ^ j;
        if (ixj > i) {
          unsigned long long a = keys[i], b = keys[ixj];
          const bool up = ((i & k) == 0);
          if ((a > b) == up) { keys[i] = b; keys[ixj] = a; }
        }
      }
      __syncthreads();
    }
  }
  if (tid < CS) {
    int id = (int)(keys[tid] & 0xFFFFFFFFu);
    if ((unsigned)id >= NC) id = 0;  // safety (pathological fallback only)
    idx_out[blockIdx.x * CS + tid] = id;
  }
}

// =========================== gather + context + prediction head ===========================
__global__ __launch_bounds__(256) void k_final(const float* __restrict__ XH,
                                               const float* __restrict__ XK,
                                               const float* __restrict__ CK,
                                               const float* __restrict__ CY,
                                               const int* __restrict__ IDX,
                                               const float* __restrict__ Tw1,
                                               const float* __restrict__ Tb1,
                                               const float* __restrict__ Tw2,
                                               const float* __restrict__ labw,
                                               const float* __restrict__ labb,
                                               const float* __restrict__ pg,
                                               const float* __restrict__ pb,
                                               const float* __restrict__ pw1,
                                               const float* __restrict__ pb1,
                                               const float* __restrict__ pw2,
                                               const float* __restrict__ pb2,
                                               const float* __restrict__ hg,
                                               const float* __restrict__ hb,
                                               const float* __restrict__ hw,
                                               const float* __restrict__ hbias,
                                               float* __restrict__ OUT) {
  __shared__ float diffs[CS * 132];
  __shared__ int ids[CS];
  __shared__ float yv[CS], simc[CS], pr[CS];
  __shared__ float kv[DD], xv[DD];
  __shared__ float qh[2][DBH];
  __shared__ float xrow[DD], hln[DD], t2[DBH], x2[DD];
  __shared__ float red[DD];
  __shared__ float smv[1];
  const int tid = threadIdx.x;
  const int b = blockIdx.x;
  if (tid < CS) ids[tid] = IDX[b * CS + tid];
  if (tid < DD) { kv[tid] = XK[(size_t)b * DD + tid]; xv[tid] = XH[(size_t)b * DD + tid]; }
  __syncthreads();
  if (tid < CS) yv[tid] = CY[ids[tid]];
  for (int e = tid; e < CS * DD; e += 256) {
    const int c = e >> 7, j = e & 127;
    diffs[c * 132 + j] = kv[j] - CK[(size_t)ids[c] * DD + j];
  }
  __syncthreads();
  if (tid < CS) {
    float s = 0.f;
    for (int j = 0; j < DD; ++j) { float d = diffs[tid * 132 + j]; s -= d * d; }
    simc[tid] = s;
  }
  __syncthreads();
  if (tid == 0) {  // softmax over 96 + weighted label
    float mx = simc[0];
    for (int c = 1; c < CS; ++c) mx = fmaxf(mx, simc[c]);
    float sum = 0.f;
    for (int c = 0; c < CS; ++c) { float e = expf(simc[c] - mx); pr[c] = e; sum += e; }
    const float inv = 1.f / sum;
    float py = 0.f;
    for (int c = 0; c < CS; ++c) { pr[c] *= inv; py += pr[c] * yv[c]; }
    smv[0] = py;
  }
  __syncthreads();
  {  // phase A: q[u] = sum_c p[c]*relu(diff[c]@Tw1[:,u] + Tb1[u]); split c over 2 halves
    const int u0 = tid & 127, ch = tid >> 7;
    float q0 = 0.f, q1 = 0.f;
    for (int cb = 0; cb < 2; ++cb) {
      const int cbase = ch * 48 + cb * 24;
      float s0[24], s1[24];
      const float bb0 = Tb1[u0], bb1 = Tb1[u0 + 128];
#pragma unroll
      for (int i = 0; i < 24; ++i) { s0[i] = bb0; s1[i] = bb1; }
      for (int j4 = 0; j4 < 32; ++j4) {
        float w0[4], w1[4];
#pragma unroll
        for (int jj = 0; jj < 4; ++jj) {
          w0[jj] = Tw1[(j4 * 4 + jj) * DBH + u0];
          w1[jj] = Tw1[(j4 * 4 + jj) * DBH + u0 + 128];
        }
#pragma unroll
        for (int i = 0; i < 24; ++i) {
          float4 d4 = *(const float4*)(diffs + (cbase + i) * 132 + j4 * 4);
          s0[i] += d4.x * w0[0] + d4.y * w0[1] + d4.z * w0[2] + d4.w * w0[3];
          s1[i] += d4.x * w1[0] + d4.y * w1[1] + d4.z * w1[2] + d4.w * w1[3];
        }
      }
#pragma unroll
      for (int i = 0; i < 24; ++i) {
        const float p = pr[cbase + i];
        q0 += p * fmaxf(s0[i], 0.f);
        q1 += p * fmaxf(s1[i], 0.f);
      }
    }
    qh[ch][u0] = q0;
    qh[ch][u0 + 128] = q1;
  }
  __syncthreads();
  if (tid < DD) {  // context_x + residual
    const int d = tid;
    float cx = smv[0] * labw[d] + labb[d];
    for (int u4 = 0; u4 < 64; ++u4) {
      float4 qa = *(const float4*)(&qh[0][u4 * 4]);
      float4 qb = *(const float4*)(&qh[1][u4 * 4]);
      cx += (qa.x + qb.x) * Tw2[(u4 * 4 + 0) * DD + d];
      cx += (qa.y + qb.y) * Tw2[(u4 * 4 + 1) * DD + d];
      cx += (qa.z + qb.z) * Tw2[(u4 * 4 + 2) * DD + d];
      cx += (qa.w + qb.w) * Tw2[(u4 * 4 + 3) * DD + d];
    }
    xrow[d] = xv[d] + cx;
  }
  __syncthreads();
  // LN1
  if (tid < DD) red[tid] = xrow[tid];
  __syncthreads();
  for (int s = 64; s > 0; s >>= 1) { if (tid < s) red[tid] += red[tid + s]; __syncthreads(); }
  const float m1 = red[0] * (1.f / 128.f);
  __syncthreads();
  if (tid < DD) { float d = xrow[tid] - m1; red[tid] = d * d; }
  __syncthreads();
  for (int s = 64; s > 0; s >>= 1) { if (tid < s) red[tid] += red[tid + s]; __syncthreads(); }
  const float rstd1 = 1.f / sqrtf(red[0] * (1.f / 128.f) + 1e-5f);
  __syncthreads();
  if (tid < DD) hln[tid] = (xrow[tid] - m1) * rstd1 * pg[tid] + pb[tid];
  __syncthreads();
  {  // pred MLP up
    const int u = tid;
    float s = pb1[u];
    for (int j4 = 0; j4 < 32; ++j4) {
      float4 h4 = *(const float4*)(hln + j4 * 4);
      s += h4.x * pw1[(j4 * 4 + 0) * DBH + u];
      s += h4.y * pw1[(j4 * 4 + 1) * DBH + u];
      s += h4.z * pw1[(j4 * 4 + 2) * DBH + u];
      s += h4.w * pw1[(j4 * 4 + 3) * DBH + u];
    }
    t2[u] = fmaxf(s, 0.f);
  }
  __syncthreads();
  if (tid < DD) {  // pred MLP down + residual
    const int d = tid;
    float s = pb2[d];
    for (int u4 = 0; u4 < 64; ++u4) {
      float4 t4 = *(const float4*)(t2 + u4 * 4);
      s += t4.x * pw2[(u4 * 4 + 0) * DD + d];
      s += t4.y * pw2[(u4 * 4 + 1) * DD + d];
      s += t4.z * pw2[(u4 * 4 + 2) * DD + d];
      s += t4.w * pw2[(u4 * 4 + 3) * DD + d];
    }
    x2[d] = xrow[d] + s;
  }
  __syncthreads();
  // LN2 + relu + head
  if (tid < DD) red[tid] = x2[tid];
  __syncthreads();
  for (int s = 64; s > 0; s >>= 1) { if (tid < s) red[tid] += red[tid + s]; __syncthreads(); }
  const float m2 = red[0] * (1.f / 128.f);
  __syncthreads();
  if (tid < DD) { float d = x2[tid] - m2; red[tid] = d * d; }
  __syncthreads();
  for (int s = 64; s > 0; s >>= 1) { if (tid < s) red[tid] += red[tid + s]; __syncthreads(); }
  const float rstd2 = 1.f / sqrtf(red[0] * (1.f / 128.f) + 1e-5f);
  __syncthreads();
  if (tid < DD) {
    float z = (x2[tid] - m2) * rstd2 * hg[tid] + hb[tid];
    z = fmaxf(z, 0.f);
    red[tid] = z * hw[tid];
  }
  __syncthreads();
  for (int s = 64; s > 0; s >>= 1) { if (tid < s) red[tid] += red[tid + s]; __syncthreads(); }
  if (tid == 0) OUT[b] = red[0] + hbias[0];
}

// ======================================= launcher =======================================
extern "C" void kernel_launch(void* const* d_in, const int* in_sizes, int n_in,
                              void* d_out, int out_size, void* d_ws, size_t ws_size,
                              hipStream_t stream) {
  (void)in_sizes; (void)n_in; (void)out_size; (void)ws_size;
  const float* x_num      = (const float*)d_in[0];
  const float* cand_x     = (const float*)d_in[1];
  const float* cand_y     = (const float*)d_in[2];
  const float* W_in       = (const float*)d_in[3];
  const float* b_in       = (const float*)d_in[4];
  const float* enc_w1     = (const float*)d_in[5];
  const float* enc_b1     = (const float*)d_in[6];
  const float* enc_w2     = (const float*)d_in[7];
  const float* enc_b2     = (const float*)d_in[8];
  const float* ln_mix_g   = (const float*)d_in[9];
  const float* ln_mix_b   = (const float*)d_in[10];
  const float* K_w        = (const float*)d_in[11];
  const float* K_b        = (const float*)d_in[12];
  const float* lab_w      = (const float*)d_in[13];
  const float* lab_b      = (const float*)d_in[14];
  const float* T_w1       = (const float*)d_in[15];
  const float* T_b1       = (const float*)d_in[16];
  const float* T_w2       = (const float*)d_in[17];
  const float* pred_ln_g  = (const float*)d_in[18];
  const float* pred_ln_b  = (const float*)d_in[19];
  const float* pred_w1    = (const float*)d_in[20];
  const float* pred_b1    = (const float*)d_in[21];
  const float* pred_w2    = (const float*)d_in[22];
  const float* pred_b2    = (const float*)d_in[23];
  const float* head_ln_g  = (const float*)d_in[24];
  const float* head_ln_b  = (const float*)d_in[25];
  const float* head_w     = (const float*)d_in[26];
  const float* head_b     = (const float*)d_in[27];
  float* out = (float*)d_out;

  char* w8 = (char*)d_ws;
  size_t off = 0;
  float* cand_k = (float*)(w8 + off);              off += (size_t)NC * DD * 4;   // 102.4 MB
  float* cand_ck2 = (float*)(w8 + off);            off += (size_t)NC * 4;        // 0.8 MB
  float* xh = (float*)(w8 + off);                  off += (size_t)BB * DD * 4;
  float* xk = (float*)(w8 + off);                  off += (size_t)BB * DD * 4;
  float* xk2 = (float*)(w8 + off);                 off += 4096;
  __hip_bfloat16* xkb16 = (__hip_bfloat16*)(w8 + off); off += (size_t)BB * DD * 2;
  int* idx_all = (int*)(w8 + off);                 off += (size_t)BB * CS * 4;
  char* big = w8 + off;                            // 153.6 MB region
  float* cand_h = (float*)big;                                       // [NC,128] f32 (dies after e4)
  __hip_bfloat16* ckb16 = (__hip_bfloat16*)(big + (size_t)NC * DD * 4);  // [NC,128] bf16
  __hip_bfloat16* sims = (__hip_bfloat16*)big;                        // [256,NC] bf16 (after e4)

  // ---- encoder: candidates ----
  k_e1<<<NC / 32, 256, 0, stream>>>(cand_x, W_in, b_in, cand_h);
  k_e23<<<NC / 32, 256, 0, stream>>>(cand_h, enc_w1, enc_b1, enc_w2, enc_b2);
  k_e4<<<NC / 32, 256, 0, stream>>>(cand_h, ln_mix_g, ln_mix_b, K_w, K_b,
                                    cand_k, ckb16, cand_ck2);
  // ---- encoder: queries ----
  k_e1<<<BB / 32, 256, 0, stream>>>(x_num, W_in, b_in, xh);
  k_e23<<<BB / 32, 256, 0, stream>>>(xh, enc_w1, enc_b1, enc_w2, enc_b2);
  k_e4<<<BB / 32, 256, 0, stream>>>(xh, ln_mix_g, ln_mix_b, K_w, K_b,
                                    xk, xkb16, xk2);
  // ---- scores + top-96, in 4 chunks of 256 query rows ----
  for (int c = 0; c < 4; ++c) {
    k_sims<<<dim3(NC / 64, 4), 256, 0, stream>>>(
        (const __hip_bfloat16*)(xkb16 + (size_t)c * 256 * DD), ckb16, cand_ck2, sims);
    k_select<<<256, 256, 0, stream>>>(sims, idx_all + (size_t)c * 256 * CS);
  }
  // ---- gather + context + head ----
  k_final<<<BB, 256, 0, stream>>>(xh, xk, cand_k, cand_y, idx_all,
                                  T_w1, T_b1, T_w2, lab_w, lab_b,
                                  pred_ln_g, pred_ln_b, pred_w1, pred_b1, pred_w2, pred_b2,
                                  head_ln_g, head_ln_b, head_w, head_b, out);
}

// Round 2
// 1817.149 us; speedup vs baseline: 1.2988x; 1.2988x over previous
//
#include <hip/hip_runtime.h>
#include <hip/hip_bf16.h>

#define NC 200000
#define BB 1024
#define DD 128
#define DBH 256
#define CS 96

typedef __attribute__((ext_vector_type(8))) short bf16x8;
typedef __attribute__((ext_vector_type(4))) float f32x4;

#define LDH 136  // padded bf16 stride for 128-wide tiles
#define LDU 264  // padded bf16 stride for 256-wide tiles

__device__ inline uint4 pack8(const float4 a, const float4 b) {
  union { __hip_bfloat16 h[8]; uint4 v; } r;
  r.h[0] = __float2bfloat16(a.x); r.h[1] = __float2bfloat16(a.y);
  r.h[2] = __float2bfloat16(a.z); r.h[3] = __float2bfloat16(a.w);
  r.h[4] = __float2bfloat16(b.x); r.h[5] = __float2bfloat16(b.y);
  r.h[6] = __float2bfloat16(b.z); r.h[7] = __float2bfloat16(b.w);
  return r.v;
}

// ====================== weight prep: bf16 transposed copies ======================
__global__ __launch_bounds__(256) void k_prep(const float* __restrict__ w1,
                                              const float* __restrict__ w2,
                                              const float* __restrict__ kw,
                                              __hip_bfloat16* __restrict__ w1t,
                                              __hip_bfloat16* __restrict__ w2t,
                                              __hip_bfloat16* __restrict__ kwt) {
  const int i = blockIdx.x * 256 + threadIdx.x;  // grid covers 32768
  if (i < 32768) {  // w1t[u][j] = w1[j][u]  (u<256, j<128)
    const int u = i >> 7, j = i & 127;
    w1t[i] = __float2bfloat16(w1[j * DBH + u]);
  }
  if (i < 32768) {  // w2t[d][u] = w2[u][d]  (d<128, u<256)
    const int d = i >> 8, u = i & 255;
    w2t[i] = __float2bfloat16(w2[u * DD + d]);
  }
  if (i < 16384) {  // kwt[d][j] = kw[j][d]  (d<128, j<128)
    const int d = i >> 7, j = i & 127;
    kwt[i] = __float2bfloat16(kw[j * DD + d]);
  }
}

// ============================ encoder stage 1: H = X @ W_in + b ============================
__global__ __launch_bounds__(256) void k_e1(const float* __restrict__ X,
                                            const float* __restrict__ W,
                                            const float* __restrict__ bias,
                                            float* __restrict__ H) {
  __shared__ float Xs[32 * 32];
  const int tid = threadIdx.x;
  const int r0 = blockIdx.x * 32;
  ((float4*)Xs)[tid] = ((const float4*)(X + (size_t)r0 * 32))[tid];
  __syncthreads();
  const int d0 = tid & 63;
  const int rh = tid >> 6;
  float acc0[8], acc1[8];
  const float b0 = bias[d0], b1 = bias[d0 + 64];
#pragma unroll
  for (int r = 0; r < 8; ++r) { acc0[r] = b0; acc1[r] = b1; }
#pragma unroll
  for (int k4 = 0; k4 < 8; ++k4) {
    float w0[4], w1[4];
#pragma unroll
    for (int kk = 0; kk < 4; ++kk) {
      w0[kk] = W[(k4 * 4 + kk) * DD + d0];
      w1[kk] = W[(k4 * 4 + kk) * DD + d0 + 64];
    }
#pragma unroll
    for (int r = 0; r < 8; ++r) {
      float4 x4 = ((const float4*)(Xs + (rh * 8 + r) * 32))[k4];
      acc0[r] += x4.x * w0[0] + x4.y * w0[1] + x4.z * w0[2] + x4.w * w0[3];
      acc1[r] += x4.x * w1[0] + x4.y * w1[1] + x4.z * w1[2] + x4.w * w1[3];
    }
  }
#pragma unroll
  for (int r = 0; r < 8; ++r) {
    const size_t row = (size_t)(r0 + rh * 8 + r);
    H[row * DD + d0] = acc0[r];
    H[row * DD + d0 + 64] = acc1[r];
  }
}

// ============== encoder stage 2+3 (MFMA): H = H + relu(H@W1 + b1)@W2 + b2 ==============
// block = 64 rows, 4 waves. W1t: [256][128] bf16 (W1 cols as rows). W2t: [128][256] bf16.
__global__ __launch_bounds__(256) void k_e23m(float* __restrict__ H,
                                              const __hip_bfloat16* __restrict__ W1t,
                                              const float* __restrict__ B1,
                                              const __hip_bfloat16* __restrict__ W2t,
                                              const float* __restrict__ B2) {
  __shared__ __hip_bfloat16 Hs[64 * LDH];
  __shared__ __hip_bfloat16 Us[64 * LDU];
  const int tid = threadIdx.x;
  const int r0 = blockIdx.x * 64;
  // stage H (f32 -> bf16) into LDS
#pragma unroll
  for (int i = 0; i < 4; ++i) {
    const int e8 = i * 256 + tid;  // 1024 groups of 8
    const int row = e8 >> 4, c8 = e8 & 15;
    const float* src = H + (size_t)(r0 + row) * DD + c8 * 8;
    float4 f0 = *(const float4*)(src);
    float4 f1 = *(const float4*)(src + 4);
    *(uint4*)(Hs + row * LDH + c8 * 8) = pack8(f0, f1);
  }
  __syncthreads();
  const int l = tid & 63, w = tid >> 6;
  const int lr = l & 15, lg = l >> 4;
  {  // phase 1: U = relu(H @ W1 + b1), wave w owns cols [w*64, w*64+64)
    f32x4 acc[4][4] = {};
#pragma unroll
    for (int kk = 0; kk < 4; ++kk) {
      bf16x8 a[4], b[4];
#pragma unroll
      for (int mi = 0; mi < 4; ++mi)
        a[mi] = *(const bf16x8*)(Hs + (mi * 16 + lr) * LDH + kk * 32 + lg * 8);
#pragma unroll
      for (int ni = 0; ni < 4; ++ni)
        b[ni] = *(const bf16x8*)(W1t + (size_t)(w * 64 + ni * 16 + lr) * DD + kk * 32 + lg * 8);
#pragma unroll
      for (int mi = 0; mi < 4; ++mi)
#pragma unroll
        for (int ni = 0; ni < 4; ++ni)
          acc[mi][ni] = __builtin_amdgcn_mfma_f32_16x16x32_bf16(a[mi], b[ni], acc[mi][ni], 0, 0, 0);
    }
#pragma unroll
    for (int ni = 0; ni < 4; ++ni) {
      const int col = w * 64 + ni * 16 + lr;
      const float bb = B1[col];
#pragma unroll
      for (int mi = 0; mi < 4; ++mi)
#pragma unroll
        for (int r = 0; r < 4; ++r) {
          const int row = mi * 16 + lg * 4 + r;
          Us[row * LDU + col] = __float2bfloat16(fmaxf(acc[mi][ni][r] + bb, 0.f));
        }
    }
  }
  __syncthreads();
  {  // phase 2: H += U @ W2 + b2, wave w owns cols [w*32, w*32+32)
    f32x4 acc[4][2] = {};
#pragma unroll
    for (int kk = 0; kk < 8; ++kk) {
      bf16x8 a[4], b[2];
#pragma unroll
      for (int mi = 0; mi < 4; ++mi)
        a[mi] = *(const bf16x8*)(Us + (mi * 16 + lr) * LDU + kk * 32 + lg * 8);
#pragma unroll
      for (int ni = 0; ni < 2; ++ni)
        b[ni] = *(const bf16x8*)(W2t + (size_t)(w * 32 + ni * 16 + lr) * DBH + kk * 32 + lg * 8);
#pragma unroll
      for (int mi = 0; mi < 4; ++mi)
#pragma unroll
        for (int ni = 0; ni < 2; ++ni)
          acc[mi][ni] = __builtin_amdgcn_mfma_f32_16x16x32_bf16(a[mi], b[ni], acc[mi][ni], 0, 0, 0);
    }
#pragma unroll
    for (int ni = 0; ni < 2; ++ni) {
      const int col = w * 32 + ni * 16 + lr;
      const float bb = B2[col];
#pragma unroll
      for (int mi = 0; mi < 4; ++mi)
#pragma unroll
        for (int r = 0; r < 4; ++r) {
          const int row = mi * 16 + lg * 4 + r;
          const size_t g = (size_t)(r0 + row) * DD + col;
          H[g] = H[g] + acc[mi][ni][r] + bb;
        }
    }
  }
}

// ====== encoder stage 4 (MFMA): K = LN(H)@Kw + Kb ; bf16 copy + rowwise sum(K^2) ======
// block = 64 rows, 4 waves. Kwt: [128][128] bf16 (Kw cols as rows).
__global__ __launch_bounds__(256) void k_e4m(const float* __restrict__ H,
                                             const float* __restrict__ g,
                                             const float* __restrict__ bln,
                                             const __hip_bfloat16* __restrict__ Kwt,
                                             const float* __restrict__ Kb,
                                             float* __restrict__ Kout,
                                             __hip_bfloat16* __restrict__ Kb16,
                                             float* __restrict__ k2out) {
  __shared__ __hip_bfloat16 Ls[64 * LDH];
  __shared__ float k2s[64];
  const int tid = threadIdx.x;
  const int r0 = blockIdx.x * 64;
  if (tid < 64) k2s[tid] = 0.f;
  // LN: 4 threads per row, 32 elems each
  {
    const int row = tid >> 2, q = tid & 3;
    const float* hr = H + (size_t)(r0 + row) * DD + q * 32;
    float v[32];
#pragma unroll
    for (int i = 0; i < 8; ++i) {
      float4 f = ((const float4*)hr)[i];
      v[i * 4 + 0] = f.x; v[i * 4 + 1] = f.y; v[i * 4 + 2] = f.z; v[i * 4 + 3] = f.w;
    }
    float s = 0.f;
#pragma unroll
    for (int i = 0; i < 32; ++i) s += v[i];
    s += __shfl_xor(s, 1); s += __shfl_xor(s, 2);
    const float mean = s * (1.f / 128.f);
    float vs = 0.f;
#pragma unroll
    for (int i = 0; i < 32; ++i) { float d = v[i] - mean; vs += d * d; }
    vs += __shfl_xor(vs, 1); vs += __shfl_xor(vs, 2);
    const float rstd = 1.f / sqrtf(vs * (1.f / 128.f) + 1e-5f);
#pragma unroll
    for (int i = 0; i < 4; ++i) {
      float t[8];
#pragma unroll
      for (int j = 0; j < 8; ++j) {
        const int col = q * 32 + i * 8 + j;
        t[j] = (v[i * 8 + j] - mean) * rstd * g[col] + bln[col];
      }
      float4 f0 = {t[0], t[1], t[2], t[3]}, f1 = {t[4], t[5], t[6], t[7]};
      *(uint4*)(Ls + row * LDH + q * 32 + i * 8) = pack8(f0, f1);
    }
  }
  __syncthreads();
  const int l = tid & 63, w = tid >> 6;
  const int lr = l & 15, lg = l >> 4;
  f32x4 acc[4][2] = {};
#pragma unroll
  for (int kk = 0; kk < 4; ++kk) {
    bf16x8 a[4], b[2];
#pragma unroll
    for (int mi = 0; mi < 4; ++mi)
      a[mi] = *(const bf16x8*)(Ls + (mi * 16 + lr) * LDH + kk * 32 + lg * 8);
#pragma unroll
    for (int ni = 0; ni < 2; ++ni)
      b[ni] = *(const bf16x8*)(Kwt + (size_t)(w * 32 + ni * 16 + lr) * DD + kk * 32 + lg * 8);
#pragma unroll
    for (int mi = 0; mi < 4; ++mi)
#pragma unroll
      for (int ni = 0; ni < 2; ++ni)
        acc[mi][ni] = __builtin_amdgcn_mfma_f32_16x16x32_bf16(a[mi], b[ni], acc[mi][ni], 0, 0, 0);
  }
  float p[4][4];
#pragma unroll
  for (int mi = 0; mi < 4; ++mi)
#pragma unroll
    for (int r = 0; r < 4; ++r) p[mi][r] = 0.f;
#pragma unroll
  for (int ni = 0; ni < 2; ++ni) {
    const int col = w * 32 + ni * 16 + lr;
    const float kb = Kb[col];
#pragma unroll
    for (int mi = 0; mi < 4; ++mi)
#pragma unroll
      for (int r = 0; r < 4; ++r) {
        const float val = acc[mi][ni][r] + kb;
        const int row = mi * 16 + lg * 4 + r;
        const size_t gg = (size_t)(r0 + row) * DD + col;
        Kout[gg] = val;
        Kb16[gg] = __float2bfloat16(val);
        p[mi][r] += val * val;
      }
  }
#pragma unroll
  for (int mi = 0; mi < 4; ++mi)
#pragma unroll
    for (int r = 0; r < 4; ++r) {
      float t = p[mi][r];
      t += __shfl_xor(t, 1); t += __shfl_xor(t, 2);
      t += __shfl_xor(t, 4); t += __shfl_xor(t, 8);
      if (lr == 0) atomicAdd(&k2s[mi * 16 + lg * 4 + r], t);
    }
  __syncthreads();
  if (tid < 64) k2out[r0 + tid] = k2s[tid];
}

// ================= sims GEMM: S[m][n] = bf16( dot(A[m],B[n]) - 0.5*ck2[n] ) =================
#define LDT 136
__global__ __launch_bounds__(256) void k_sims(const __hip_bfloat16* __restrict__ A,
                                              const __hip_bfloat16* __restrict__ Bm,
                                              const float* __restrict__ ck2,
                                              __hip_bfloat16* __restrict__ S) {
  __shared__ __hip_bfloat16 As[64 * LDT];
  __shared__ __hip_bfloat16 Bs[64 * LDT];
  const int tid = threadIdx.x;
  const int n0 = blockIdx.x * 64;
  const int m0 = blockIdx.y * 64;
  {
    const uint4* ga = (const uint4*)(A + (size_t)m0 * DD);
    const uint4* gb = (const uint4*)(Bm + (size_t)n0 * DD);
#pragma unroll
    for (int i = 0; i < 4; ++i) {
      const int e8 = i * 256 + tid;
      const int row = e8 >> 4;
      const int c8 = e8 & 15;
      uint4 va = ga[e8];
      uint4 vb = gb[e8];
      *(uint4*)(As + row * LDT + c8 * 8) = va;
      *(uint4*)(Bs + row * LDT + c8 * 8) = vb;
    }
  }
  __syncthreads();
  const int l = tid & 63, w = tid >> 6;
  const int wm = w >> 1, wn = w & 1;
  const int lr = l & 15, lg = l >> 4;
  f32x4 acc[2][2] = {};
#pragma unroll
  for (int kk = 0; kk < 4; ++kk) {
    bf16x8 a[2], b[2];
#pragma unroll
    for (int mi = 0; mi < 2; ++mi)
      a[mi] = *(const bf16x8*)(As + (wm * 32 + mi * 16 + lr) * LDT + kk * 32 + lg * 8);
#pragma unroll
    for (int ni = 0; ni < 2; ++ni)
      b[ni] = *(const bf16x8*)(Bs + (wn * 32 + ni * 16 + lr) * LDT + kk * 32 + lg * 8);
#pragma unroll
    for (int mi = 0; mi < 2; ++mi)
#pragma unroll
      for (int ni = 0; ni < 2; ++ni)
        acc[mi][ni] = __builtin_amdgcn_mfma_f32_16x16x32_bf16(a[mi], b[ni], acc[mi][ni], 0, 0, 0);
  }
#pragma unroll
  for (int mi = 0; mi < 2; ++mi)
#pragma unroll
    for (int ni = 0; ni < 2; ++ni) {
      const int gcol = n0 + wn * 32 + ni * 16 + lr;
      const float c2 = 0.5f * ck2[gcol];
#pragma unroll
      for (int r = 0; r < 4; ++r) {
        const int grow = m0 + wm * 32 + mi * 16 + lg * 4 + r;
        S[(size_t)grow * NC + gcol] = __float2bfloat16(acc[mi][ni][r] - c2);
      }
    }
}

// ======================= per-row top-96 selection from bf16 score row =======================
__device__ inline unsigned long long mkkey(float v, int idx) {
  unsigned b = __float_as_uint(v);
  unsigned u = (b & 0x80000000u) ? ~b : (b | 0x80000000u);
  return (((unsigned long long)(~u)) << 32) | (unsigned)idx;
}

#define SCAP 4096
__global__ __launch_bounds__(256) void k_select(const __hip_bfloat16* __restrict__ S,
                                                int* __restrict__ idx_out) {
  __shared__ unsigned long long keys[SCAP];
  __shared__ float redmax[256];
  __shared__ int cnt_sh;
  const int tid = threadIdx.x;
  const unsigned* row = (const unsigned*)(S + (size_t)blockIdx.x * NC);
  const int NW = NC / 8;
  float m = -1e30f;
  for (int v = tid; v < NW; v += 256) {
    uint4 d = ((const uint4*)row)[v];
    unsigned wd0 = d.x, wd1 = d.y, wd2 = d.z, wd3 = d.w;
    m = fmaxf(m, __uint_as_float(wd0 << 16)); m = fmaxf(m, __uint_as_float(wd0 & 0xffff0000u));
    m = fmaxf(m, __uint_as_float(wd1 << 16)); m = fmaxf(m, __uint_as_float(wd1 & 0xffff0000u));
    m = fmaxf(m, __uint_as_float(wd2 << 16)); m = fmaxf(m, __uint_as_float(wd2 & 0xffff0000u));
    m = fmaxf(m, __uint_as_float(wd3 << 16)); m = fmaxf(m, __uint_as_float(wd3 & 0xffff0000u));
  }
  redmax[tid] = m;
  __syncthreads();
  for (int s = 128; s > 0; s >>= 1) {
    if (tid < s) redmax[tid] = fmaxf(redmax[tid], redmax[tid + s]);
    __syncthreads();
  }
  m = redmax[0];
  float W = 7.0f;
  int cnt = 0;
  for (int it = 0; it < 24; ++it) {
    __syncthreads();
    if (tid == 0) cnt_sh = 0;
    __syncthreads();
    const float thr = m - W;
    for (int v = tid; v < NW; v += 256) {
      uint4 d = ((const uint4*)row)[v];
      const unsigned wd[4] = {d.x, d.y, d.z, d.w};
#pragma unroll
      for (int wi = 0; wi < 4; ++wi) {
        float vlo = __uint_as_float(wd[wi] << 16);
        float vhi = __uint_as_float(wd[wi] & 0xffff0000u);
        int base = v * 8 + wi * 2;
        if (vlo >= thr) { int p = atomicAdd(&cnt_sh, 1); if (p < SCAP) keys[p] = mkkey(vlo, base); }
        if (vhi >= thr) { int p = atomicAdd(&cnt_sh, 1); if (p < SCAP) keys[p] = mkkey(vhi, base + 1); }
      }
    }
    __syncthreads();
    cnt = cnt_sh;
    if (cnt >= CS && cnt <= SCAP) break;
    W = (cnt < CS) ? W * 2.0f : W * 0.6f;
  }
  if (cnt > SCAP) cnt = SCAP;
  int size = 128;
  while (size < cnt) size <<= 1;
  for (int i = tid; i < size; i += 256)
    if (i >= cnt) keys[i] = 0xFFFFFFFFFFFFFFFFull;
  __syncthreads();
  for (int k = 2; k <= size; k <<= 1) {
    for (int j = k >> 1; j > 0; j >>= 1) {
      for (int i = tid; i < size; i += 256) {
        const int ixj = i ^ j;
        if (ixj > i) {
          unsigned long long a = keys[i], b = keys[ixj];
          const bool up = ((i & k) == 0);
          if ((a > b) == up) { keys[i] = b; keys[ixj] = a; }
        }
      }
      __syncthreads();
    }
  }
  if (tid < CS) {
    int id = (int)(keys[tid] & 0xFFFFFFFFu);
    if ((unsigned)id >= NC) id = 0;
    idx_out[blockIdx.x * CS + tid] = id;
  }
}

// =========================== gather + context + prediction head ===========================
__global__ __launch_bounds__(256) void k_final(const float* __restrict__ XH,
                                               const float* __restrict__ XK,
                                               const float* __restrict__ CK,
                                               const float* __restrict__ CY,
                                               const int* __restrict__ IDX,
                                               const float* __restrict__ Tw1,
                                               const float* __restrict__ Tb1,
                                               const float* __restrict__ Tw2,
                                               const float* __restrict__ labw,
                                               const float* __restrict__ labb,
                                               const float* __restrict__ pg,
                                               const float* __restrict__ pb,
                                               const float* __restrict__ pw1,
                                               const float* __restrict__ pb1,
                                               const float* __restrict__ pw2,
                                               const float* __restrict__ pb2,
                                               const float* __restrict__ hg,
                                               const float* __restrict__ hb,
                                               const float* __restrict__ hw,
                                               const float* __restrict__ hbias,
                                               float* __restrict__ OUT) {
  __shared__ float diffs[CS * 132];
  __shared__ int ids[CS];
  __shared__ float yv[CS], simc[CS], pr[CS];
  __shared__ float kv[DD], xv[DD];
  __shared__ float qh[2][DBH];
  __shared__ float xrow[DD], hln[DD], t2[DBH], x2[DD];
  __shared__ float red[DD];
  __shared__ float smv[1];
  const int tid = threadIdx.x;
  const int b = blockIdx.x;
  if (tid < CS) ids[tid] = IDX[b * CS + tid];
  if (tid < DD) { kv[tid] = XK[(size_t)b * DD + tid]; xv[tid] = XH[(size_t)b * DD + tid]; }
  __syncthreads();
  if (tid < CS) yv[tid] = CY[ids[tid]];
  for (int e = tid; e < CS * DD; e += 256) {
    const int c = e >> 7, j = e & 127;
    diffs[c * 132 + j] = kv[j] - CK[(size_t)ids[c] * DD + j];
  }
  __syncthreads();
  if (tid < CS) {
    float s = 0.f;
    for (int j = 0; j < DD; ++j) { float d = diffs[tid * 132 + j]; s -= d * d; }
    simc[tid] = s;
  }
  __syncthreads();
  if (tid == 0) {
    float mx = simc[0];
    for (int c = 1; c < CS; ++c) mx = fmaxf(mx, simc[c]);
    float sum = 0.f;
    for (int c = 0; c < CS; ++c) { float e = expf(simc[c] - mx); pr[c] = e; sum += e; }
    const float inv = 1.f / sum;
    float py = 0.f;
    for (int c = 0; c < CS; ++c) { pr[c] *= inv; py += pr[c] * yv[c]; }
    smv[0] = py;
  }
  __syncthreads();
  {
    const int u0 = tid & 127, ch = tid >> 7;
    float q0 = 0.f, q1 = 0.f;
    for (int cb = 0; cb < 2; ++cb) {
      const int cbase = ch * 48 + cb * 24;
      float s0[24], s1[24];
      const float bb0 = Tb1[u0], bb1 = Tb1[u0 + 128];
#pragma unroll
      for (int i = 0; i < 24; ++i) { s0[i] = bb0; s1[i] = bb1; }
      for (int j4 = 0; j4 < 32; ++j4) {
        float w0[4], w1[4];
#pragma unroll
        for (int jj = 0; jj < 4; ++jj) {
          w0[jj] = Tw1[(j4 * 4 + jj) * DBH + u0];
          w1[jj] = Tw1[(j4 * 4 + jj) * DBH + u0 + 128];
        }
#pragma unroll
        for (int i = 0; i < 24; ++i) {
          float4 d4 = *(const float4*)(diffs + (cbase + i) * 132 + j4 * 4);
          s0[i] += d4.x * w0[0] + d4.y * w0[1] + d4.z * w0[2] + d4.w * w0[3];
          s1[i] += d4.x * w1[0] + d4.y * w1[1] + d4.z * w1[2] + d4.w * w1[3];
        }
      }
#pragma unroll
      for (int i = 0; i < 24; ++i) {
        const float p = pr[cbase + i];
        q0 += p * fmaxf(s0[i], 0.f);
        q1 += p * fmaxf(s1[i], 0.f);
      }
    }
    qh[ch][u0] = q0;
    qh[ch][u0 + 128] = q1;
  }
  __syncthreads();
  if (tid < DD) {
    const int d = tid;
    float cx = smv[0] * labw[d] + labb[d];
    for (int u4 = 0; u4 < 64; ++u4) {
      float4 qa = *(const float4*)(&qh[0][u4 * 4]);
      float4 qb = *(const float4*)(&qh[1][u4 * 4]);
      cx += (qa.x + qb.x) * Tw2[(u4 * 4 + 0) * DD + d];
      cx += (qa.y + qb.y) * Tw2[(u4 * 4 + 1) * DD + d];
      cx += (qa.z + qb.z) * Tw2[(u4 * 4 + 2) * DD + d];
      cx += (qa.w + qb.w) * Tw2[(u4 * 4 + 3) * DD + d];
    }
    xrow[d] = xv[d] + cx;
  }
  __syncthreads();
  if (tid < DD) red[tid] = xrow[tid];
  __syncthreads();
  for (int s = 64; s > 0; s >>= 1) { if (tid < s) red[tid] += red[tid + s]; __syncthreads(); }
  const float m1 = red[0] * (1.f / 128.f);
  __syncthreads();
  if (tid < DD) { float d = xrow[tid] - m1; red[tid] = d * d; }
  __syncthreads();
  for (int s = 64; s > 0; s >>= 1) { if (tid < s) red[tid] += red[tid + s]; __syncthreads(); }
  const float rstd1 = 1.f / sqrtf(red[0] * (1.f / 128.f) + 1e-5f);
  __syncthreads();
  if (tid < DD) hln[tid] = (xrow[tid] - m1) * rstd1 * pg[tid] + pb[tid];
  __syncthreads();
  {
    const int u = tid;
    float s = pb1[u];
    for (int j4 = 0; j4 < 32; ++j4) {
      float4 h4 = *(const float4*)(hln + j4 * 4);
      s += h4.x * pw1[(j4 * 4 + 0) * DBH + u];
      s += h4.y * pw1[(j4 * 4 + 1) * DBH + u];
      s += h4.z * pw1[(j4 * 4 + 2) * DBH + u];
      s += h4.w * pw1[(j4 * 4 + 3) * DBH + u];
    }
    t2[u] = fmaxf(s, 0.f);
  }
  __syncthreads();
  if (tid < DD) {
    const int d = tid;
    float s = pb2[d];
    for (int u4 = 0; u4 < 64; ++u4) {
      float4 t4 = *(const float4*)(t2 + u4 * 4);
      s += t4.x * pw2[(u4 * 4 + 0) * DD + d];
      s += t4.y * pw2[(u4 * 4 + 1) * DD + d];
      s += t4.z * pw2[(u4 * 4 + 2) * DD + d];
      s += t4.w * pw2[(u4 * 4 + 3) * DD + d];
    }
    x2[d] = xrow[d] + s;
  }
  __syncthreads();
  if (tid < DD) red[tid] = x2[tid];
  __syncthreads();
  for (int s = 64; s > 0; s >>= 1) { if (tid < s) red[tid] += red[tid + s]; __syncthreads(); }
  const float m2 = red[0] * (1.f / 128.f);
  __syncthreads();
  if (tid < DD) { float d = x2[tid] - m2; red[tid] = d * d; }
  __syncthreads();
  for (int s = 64; s > 0; s >>= 1) { if (tid < s) red[tid] += red[tid + s]; __syncthreads(); }
  const float rstd2 = 1.f / sqrtf(red[0] * (1.f / 128.f) + 1e-5f);
  __syncthreads();
  if (tid < DD) {
    float z = (x2[tid] - m2) * rstd2 * hg[tid] + hb[tid];
    z = fmaxf(z, 0.f);
    red[tid] = z * hw[tid];
  }
  __syncthreads();
  for (int s = 64; s > 0; s >>= 1) { if (tid < s) red[tid] += red[tid + s]; __syncthreads(); }
  if (tid == 0) OUT[b] = red[0] + hbias[0];
}

// ======================================= launcher =======================================
extern "C" void kernel_launch(void* const* d_in, const int* in_sizes, int n_in,
                              void* d_out, int out_size, void* d_ws, size_t ws_size,
                              hipStream_t stream) {
  (void)in_sizes; (void)n_in; (void)out_size; (void)ws_size;
  const float* x_num      = (const float*)d_in[0];
  const float* cand_x     = (const float*)d_in[1];
  const float* cand_y     = (const float*)d_in[2];
  const float* W_in       = (const float*)d_in[3];
  const float* b_in       = (const float*)d_in[4];
  const float* enc_w1     = (const float*)d_in[5];
  const float* enc_b1     = (const float*)d_in[6];
  const float* enc_w2     = (const float*)d_in[7];
  const float* enc_b2     = (const float*)d_in[8];
  const float* ln_mix_g   = (const float*)d_in[9];
  const float* ln_mix_b   = (const float*)d_in[10];
  const float* K_w        = (const float*)d_in[11];
  const float* K_b        = (const float*)d_in[12];
  const float* lab_w      = (const float*)d_in[13];
  const float* lab_b      = (const float*)d_in[14];
  const float* T_w1       = (const float*)d_in[15];
  const float* T_b1       = (const float*)d_in[16];
  const float* T_w2       = (const float*)d_in[17];
  const float* pred_ln_g  = (const float*)d_in[18];
  const float* pred_ln_b  = (const float*)d_in[19];
  const float* pred_w1    = (const float*)d_in[20];
  const float* pred_b1    = (const float*)d_in[21];
  const float* pred_w2    = (const float*)d_in[22];
  const float* pred_b2    = (const float*)d_in[23];
  const float* head_ln_g  = (const float*)d_in[24];
  const float* head_ln_b  = (const float*)d_in[25];
  const float* head_w     = (const float*)d_in[26];
  const float* head_b     = (const float*)d_in[27];
  float* out = (float*)d_out;

  char* w8 = (char*)d_ws;
  size_t off = 0;
  float* cand_k = (float*)(w8 + off);              off += (size_t)NC * DD * 4;
  float* cand_ck2 = (float*)(w8 + off);            off += (size_t)NC * 4;
  float* xh = (float*)(w8 + off);                  off += (size_t)BB * DD * 4;
  float* xk = (float*)(w8 + off);                  off += (size_t)BB * DD * 4;
  float* xk2 = (float*)(w8 + off);                 off += 4096;
  __hip_bfloat16* xkb16 = (__hip_bfloat16*)(w8 + off); off += (size_t)BB * DD * 2;
  int* idx_all = (int*)(w8 + off);                 off += (size_t)BB * CS * 4;
  __hip_bfloat16* w1t = (__hip_bfloat16*)(w8 + off); off += (size_t)DBH * DD * 2;
  __hip_bfloat16* w2t = (__hip_bfloat16*)(w8 + off); off += (size_t)DD * DBH * 2;
  __hip_bfloat16* kwt = (__hip_bfloat16*)(w8 + off); off += (size_t)DD * DD * 2;
  char* big = w8 + off;
  float* cand_h = (float*)big;
  __hip_bfloat16* ckb16 = (__hip_bfloat16*)(big + (size_t)NC * DD * 4);
  __hip_bfloat16* sims = (__hip_bfloat16*)big;

  k_prep<<<128, 256, 0, stream>>>(enc_w1, enc_w2, K_w, w1t, w2t, kwt);
  // ---- encoder: candidates ----
  k_e1<<<NC / 32, 256, 0, stream>>>(cand_x, W_in, b_in, cand_h);
  k_e23m<<<NC / 64, 256, 0, stream>>>(cand_h, w1t, enc_b1, w2t, enc_b2);
  k_e4m<<<NC / 64, 256, 0, stream>>>(cand_h, ln_mix_g, ln_mix_b, kwt, K_b,
                                     cand_k, ckb16, cand_ck2);
  // ---- encoder: queries ----
  k_e1<<<BB / 32, 256, 0, stream>>>(x_num, W_in, b_in, xh);
  k_e23m<<<BB / 64, 256, 0, stream>>>(xh, w1t, enc_b1, w2t, enc_b2);
  k_e4m<<<BB / 64, 256, 0, stream>>>(xh, ln_mix_g, ln_mix_b, kwt, K_b,
                                     xk, xkb16, xk2);
  // ---- scores + top-96, in 4 chunks of 256 query rows ----
  for (int c = 0; c < 4; ++c) {
    k_sims<<<dim3(NC / 64, 4), 256, 0, stream>>>(
        (const __hip_bfloat16*)(xkb16 + (size_t)c * 256 * DD), ckb16, cand_ck2, sims);
    k_select<<<256, 256, 0, stream>>>(sims, idx_all + (size_t)c * 256 * CS);
  }
  // ---- gather + context + head ----
  k_final<<<BB, 256, 0, stream>>>(xh, xk, cand_k, cand_y, idx_all,
                                  T_w1, T_b1, T_w2, lab_w, lab_b,
                                  pred_ln_g, pred_ln_b, pred_w1, pred_b1, pred_w2, pred_b2,
                                  head_ln_g, head_ln_b, head_w, head_b, out);
}